// Round 14
// baseline (571.635 us; speedup 1.0000x reference)
//
#include <hip/hip_runtime.h>
#include <hip/hip_bf16.h>

// SelfAttention: out = softmax(causal((Ez Wq^T)(Ez Wk^T)^T / sqrt(512))) (Ez Wv^T)
// B=32, L=2048, DIM=512. f32 in/out; bf16 MFMA internally.
// ws: Qb (bf16, Q*SCALE*LOG2E), Kb (bf16), Vtb (bf16, [b][t][e][32] tile-contig;
// e<128 LINEAR (attn reads to regs), e>=128 chunk-XOR pre-baked (LDS path)).
// Wb (bf16 [g][kt][n][32], swizzled) in d_out scratch.
// R14 = R12 + V-split: dims 0..127 per-wave in registers from L2 (8 spare-VGPR
// short8), dims 128..511 LDS-staged; LDS 141->125 KB, V LDS reads -25%.

typedef __attribute__((ext_vector_type(8))) short short8;
typedef __attribute__((ext_vector_type(4))) short short4v;
typedef __attribute__((ext_vector_type(4))) float f32x4;

#define DIM 512
#define LSEQ 2048
#define NB 32
#define SCALE 0.04419417382415922f
#define LOG2E 1.4426950408889634f

__device__ __forceinline__ short f2bs(float f) {
  __hip_bfloat16 h = __float2bfloat16(f);
  return __builtin_bit_cast(short, h);
}

__device__ __forceinline__ void gld16(const void* g, void* l) {
  __builtin_amdgcn_global_load_lds(
      (const unsigned int __attribute__((address_space(1)))*)g,
      (unsigned int __attribute__((address_space(3)))*)l, 16, 0, 0);
}

// ---- W[z] f32 -> bf16, layout [g][kt][n][32 d-chunk-swizzled] --------------
__global__ __launch_bounds__(256) void wcvt_kernel(
    const float* __restrict__ Wq, const float* __restrict__ Wk,
    const float* __restrict__ Wv, const int* __restrict__ zp,
    short* __restrict__ Wb) {
  int z = *zp;
  int i = blockIdx.x * 256 + threadIdx.x;
  int g = i >> 15;
  int off = (i & 32767) * 8;                   // flat [n][d], d fast
  int n = off >> 9, d0 = off & 511;
  int kt = d0 >> 5, c = d0 & 31;
  int sw = ((c >> 3) ^ ((n >> 1) & 3));
  const float* src = (g == 0 ? Wq : (g == 1 ? Wk : Wv)) + (size_t)z * DIM * DIM + off;
  float4 a = *(const float4*)src, b = *(const float4*)(src + 4);
  short8 v;
  v[0]=f2bs(a.x); v[1]=f2bs(a.y); v[2]=f2bs(a.z); v[3]=f2bs(a.w);
  v[4]=f2bs(b.x); v[5]=f2bs(b.y); v[6]=f2bs(b.z); v[7]=f2bs(b.w);
  *(short8*)&Wb[((size_t)(g * 16 + kt) * 512 + n) * 32 + sw * 8] = v;
}

// ---- projection GEMM: C[m][n] = sum_d Ez[m][d] * W[n][d] -------------------
__global__ __launch_bounds__(512, 4) void proj_kernel(
    const float* __restrict__ Ez, const short* __restrict__ Wb,
    short* __restrict__ Qb, short* __restrict__ Kb, short* __restrict__ Vtb) {
  int g = blockIdx.z;
  const short* W = Wb + (size_t)g * 16 * 512 * 32;
  __shared__ short As[2][64 * 32];
  __shared__ short Bs[2][512 * 32];
  int tid = threadIdx.x, lane = tid & 63, wid = tid >> 6;
  int l15 = lane & 15, lg = lane >> 4;
  int m0 = blockIdx.x * 64;
  int sw = (l15 >> 1) & 3;
  f32x4 zero4 = {0.f, 0.f, 0.f, 0.f};
  f32x4 acc[4][4];
  #pragma unroll
  for (int mi = 0; mi < 4; mi++)
    #pragma unroll
    for (int ni = 0; ni < 4; ni++) acc[mi][ni] = zero4;

  int arow = tid >> 3, aq = tid & 7;
  int aoff = arow * 32 + (((aq >> 1) ^ ((arow >> 1) & 3)) << 3) + (aq & 1) * 4;
  const float* aptr = Ez + (size_t)(m0 + arow) * DIM + aq * 4;

  {  // prologue: stage kt=0
    float4 a = *(const float4*)aptr;
    short4v av;
    av[0]=f2bs(a.x); av[1]=f2bs(a.y); av[2]=f2bs(a.z); av[3]=f2bs(a.w);
    *(short4v*)&As[0][aoff] = av;
    #pragma unroll
    for (int ii = 0; ii < 4; ii++) {
      int s = wid * 4 + ii;
      gld16(W + s * 512 + lane * 8, &Bs[0][s * 512]);
    }
  }
  __syncthreads();

  #pragma unroll 2
  for (int kt = 0; kt < 16; kt++) {
    int cur = kt & 1;
    float4 a;
    if (kt < 15) {
      a = *(const float4*)(aptr + (kt + 1) * 32);
      #pragma unroll
      for (int ii = 0; ii < 4; ii++) {
        int s = wid * 4 + ii;
        gld16(W + (size_t)(kt + 1) * 16384 + s * 512 + lane * 8, &Bs[cur ^ 1][s * 512]);
      }
    }
    short8 af[4], bf[4];
    #pragma unroll
    for (int mi = 0; mi < 4; mi++)
      af[mi] = *(const short8*)&As[cur][(mi * 16 + l15) * 32 + ((lg ^ sw) << 3)];
    #pragma unroll
    for (int ni = 0; ni < 4; ni++)
      bf[ni] = *(const short8*)&Bs[cur][(wid * 64 + ni * 16 + l15) * 32 + ((lg ^ sw) << 3)];
    __builtin_amdgcn_s_setprio(1);
    #pragma unroll
    for (int mi = 0; mi < 4; mi++)
      #pragma unroll
      for (int ni = 0; ni < 4; ni++)
        acc[mi][ni] = __builtin_amdgcn_mfma_f32_16x16x32_bf16(af[mi], bf[ni], acc[mi][ni], 0, 0, 0);
    __builtin_amdgcn_s_setprio(0);
    if (kt < 15) {
      short4v av;
      av[0]=f2bs(a.x); av[1]=f2bs(a.y); av[2]=f2bs(a.z); av[3]=f2bs(a.w);
      *(short4v*)&As[cur ^ 1][aoff] = av;
    }
    __syncthreads();
  }

  if (g == 2) {
    #pragma unroll
    for (int mi = 0; mi < 4; mi++) {
      int gm0 = m0 + mi * 16 + lg * 4;
      int b = gm0 >> 11, l0 = gm0 & (LSEQ - 1);
      int t = l0 >> 5, c0 = l0 & 31;
      #pragma unroll
      for (int ni = 0; ni < 4; ni++) {
        int e = wid * 64 + ni * 16 + l15;
        short4v v;
        v[0]=f2bs(acc[mi][ni][0]); v[1]=f2bs(acc[mi][ni][1]);
        v[2]=f2bs(acc[mi][ni][2]); v[3]=f2bs(acc[mi][ni][3]);
        size_t base = ((size_t)(b * 64 + t) * 512 + e) * 32;
        // e<128 (wid<2): LINEAR (attn register path); else swizzled (LDS path)
        size_t idx = (wid < 2)
            ? (base + c0)
            : (base + (((c0 >> 3) ^ ((e >> 1) & 3)) << 3) + (c0 & 7));
        *(short4v*)&Vtb[idx] = v;
      }
    }
  } else {
    short* dst = (g == 0 ? Qb : Kb);
    float sc = (g == 0 ? SCALE * LOG2E : 1.0f);  // Q pre-scaled, exp2 domain
    #pragma unroll
    for (int mi = 0; mi < 4; mi++) {
      int gm0 = m0 + mi * 16 + lg * 4;
      #pragma unroll
      for (int ni = 0; ni < 4; ni++) {
        int gn = wid * 64 + ni * 16 + l15;
        #pragma unroll
        for (int r = 0; r < 4; r++)
          dst[(size_t)(gm0 + r) * DIM + gn] = f2bs(acc[mi][ni][r] * sc);
      }
    }
  }
}

// ---- flash attention (causal) ----------------------------------------------
// R12 structure + V-split: dims 0..127 read per-wave from global into regs
// (bvr[8], issued before QK^T -> L2 latency hidden); dims 128..511 LDS-staged.
__device__ __forceinline__ void stage_kv(const short* __restrict__ Kb,
                                         const short* __restrict__ Vtb,
                                         short* Klbuf, short* Vlbuf,
                                         int batch, int t, int wid, int lane) {
  #pragma unroll
  for (int ii = 0; ii < 4; ii++) {          // K: rows wid, wid+8, wid+16, wid+24
    int r = wid + ii * 8;                   // r&7 == wid
    const short* src = Kb + (size_t)(batch * LSEQ + t * 32 + r) * DIM + ((lane ^ wid) * 8);
    gld16(src, Klbuf + r * 512);
  }
  const short* vt = Vtb + (size_t)(batch * 64 + t) * 16384;  // contiguous 32KB tile
  #pragma unroll
  for (int ii = 0; ii < 3; ii++) {          // V e=128..511: 24 slabs, 3/wave
    int s = wid * 3 + ii;
    gld16(vt + (8 + s) * 512 + lane * 8, Vlbuf + s * 512);
  }
}

__global__ __launch_bounds__(512, 2) void attn_kernel(
    const short* __restrict__ Qb, const short* __restrict__ Kb,
    const short* __restrict__ Vtb, float* __restrict__ out) {
  __shared__ short Kl[2][32 * 512];   // 64 KB dbuf
  __shared__ short Vl[2][384 * 32];   // 48 KB dbuf (e = 128..511)
  __shared__ short P_lds[8][16][40];  // per-wave P transpose; 16B-aligned rows
  int tid = threadIdx.x, lane = tid & 63, wid = tid >> 6;
  int l15 = lane & 15, lg = lane >> 4;
  int batch = blockIdx.x;
  f32x4 zero4 = {0.f, 0.f, 0.f, 0.f};
  short8 ones;
  #pragma unroll
  for (int i = 0; i < 8; i++) ones[i] = (short)0x3F80;

  // lane-const LDS offsets (shorts):
  int a0 = (l15 >> 2) & 1, b0 = l15 & 3;
  int kqE = l15 * 512 + 8 * (lg ^ b0) + 32 * a0;  // even-kt base (+8192 for c=1)
  int kqO = l15 * 512 + 8 * (lg ^ b0) - 32 * a0;  // odd-kt base
  int voff = l15 * 32 + 8 * (lg ^ ((l15 >> 1) & 3));  // V LDS base (+512*(et-8))
  int vgo = l15 * 32 + lg * 8;                        // V global base (+512*et)
  short* pw = &P_lds[wid][lg * 4][l15];               // P write (+40*r, +16*c)
  const short* pr = &P_lds[wid][l15][lg * 8];         // P read (A-frag, aligned)

  for (int qpass = 0; qpass < 2; qpass++) {
    int qt = qpass ? (int)blockIdx.y : 15 - (int)blockIdx.y;  // long pass first
    int qb0 = qt * 128;
    int q0w = qb0 + wid * 16;
    int nt = qt * 4 + 4;

    stage_kv(Kb, Vtb, Kl[0], Vl[0], batch, 0, wid, lane);  // prologue prefetch

    const short* qrow = Qb + (size_t)(batch * LSEQ + q0w + l15) * DIM;
    short8 qf[16];  // Q rows in regs (SCALE*LOG2E pre-folded)
    #pragma unroll
    for (int kt = 0; kt < 16; kt++) qf[kt] = *(const short8*)(qrow + kt * 32 + lg * 8);

    f32x4 oacc[32];
    #pragma unroll
    for (int i = 0; i < 32; i++) oacc[i] = zero4;
    f32x4 dacc = zero4;   // per-row softmax denominator (via ones-MFMA)
    float mrun = -1e30f;  // wave-uniform running max (exp2 domain)

    __syncthreads();  // drains prologue stage (vmcnt) + syncs

    for (int t = 0; t < nt; t++) {
      int cur = t & 1;
      if (t + 1 < nt)
        stage_kv(Kb, Vtb, Kl[cur ^ 1], Vl[cur ^ 1], batch, t + 1, wid, lane);

      if (t * 32 <= q0w + 15) {  // wave-local causal skip
        // V dims 0..127 -> regs from L2 (linear region); latency hides under QK
        short8 bvr[8];
        const short* vt = Vtb + (size_t)(batch * 64 + t) * 16384;
        #pragma unroll
        for (int et = 0; et < 8; et++)
          bvr[et] = *(const short8*)(vt + et * 512 + vgo);
        const short* pE = Kl[cur] + kqE;
        const short* pO = Kl[cur] + kqO;
        f32x4 sacc[2] = {zero4, zero4};
        __builtin_amdgcn_s_setprio(1);
        #pragma unroll
        for (int kt = 0; kt < 16; kt += 2) {
          short8 k0 = *(const short8*)(pE + 32 * kt);
          short8 k1 = *(const short8*)(pE + 8192 + 32 * kt);
          sacc[0] = __builtin_amdgcn_mfma_f32_16x16x32_bf16(qf[kt], k0, sacc[0], 0, 0, 0);
          sacc[1] = __builtin_amdgcn_mfma_f32_16x16x32_bf16(qf[kt], k1, sacc[1], 0, 0, 0);
          short8 k2 = *(const short8*)(pO + 32 * (kt + 1));
          short8 k3 = *(const short8*)(pO + 8192 + 32 * (kt + 1));
          sacc[0] = __builtin_amdgcn_mfma_f32_16x16x32_bf16(qf[kt + 1], k2, sacc[0], 0, 0, 0);
          sacc[1] = __builtin_amdgcn_mfma_f32_16x16x32_bf16(qf[kt + 1], k3, sacc[1], 0, 0, 0);
        }
        __builtin_amdgcn_s_setprio(0);
        // softmax (exp2 domain; scores pre-scaled). Mask in place; lazy max.
        if (t * 32 + 31 > q0w) {  // diagonal tiles only
          #pragma unroll
          for (int r = 0; r < 4; r++) {
            int q = q0w + lg * 4 + r;
            if (t * 32 + l15 > q) sacc[0][r] = -1e30f;
            if (t * 32 + 16 + l15 > q) sacc[1][r] = -1e30f;
          }
        }
        float lm = fmaxf(
            fmaxf(fmaxf(sacc[0][0], sacc[0][1]), fmaxf(sacc[0][2], sacc[0][3])),
            fmaxf(fmaxf(sacc[1][0], sacc[1][1]), fmaxf(sacc[1][2], sacc[1][3])));
        if (__any(lm > mrun + 11.5f)) {  // rare: raise the wave max
          float mx = lm;
          #pragma unroll
          for (int off = 1; off < 64; off <<= 1) mx = fmaxf(mx, __shfl_xor(mx, off, 64));
          float alpha = exp2f(mrun - mx);
          mrun = mx;
          dacc[0] *= alpha; dacc[1] *= alpha; dacc[2] *= alpha; dacc[3] *= alpha;
          #pragma unroll
          for (int et = 0; et < 32; et++) {
            oacc[et][0] *= alpha; oacc[et][1] *= alpha;
            oacc[et][2] *= alpha; oacc[et][3] *= alpha;
          }
        }
        #pragma unroll
        for (int r = 0; r < 4; r++) {
          pw[r * 40] = f2bs(exp2f(sacc[0][r] - mrun));
          pw[r * 40 + 16] = f2bs(exp2f(sacc[1][r] - mrun));
        }
        short8 pa = *(const short8*)pr;  // wave-local RAW
        const short* vb = Vl[cur] + voff;
        __builtin_amdgcn_s_setprio(1);
        dacc = __builtin_amdgcn_mfma_f32_16x16x32_bf16(pa, ones, dacc, 0, 0, 0);
        #pragma unroll
        for (int et = 0; et < 8; et++)   // dims 0..127 from registers
          oacc[et] = __builtin_amdgcn_mfma_f32_16x16x32_bf16(pa, bvr[et], oacc[et], 0, 0, 0);
        #pragma unroll
        for (int et = 8; et < 32; et++) {  // dims 128..511 from LDS
          short8 bv = *(const short8*)(vb + (et - 8) * 512);
          oacc[et] = __builtin_amdgcn_mfma_f32_16x16x32_bf16(pa, bv, oacc[et], 0, 0, 0);
        }
        __builtin_amdgcn_s_setprio(0);
      }
      __syncthreads();  // drains prefetch (vmcnt) + releases buffers
    }
    // epilogue: per-wave divide by denominator, write 16 q-rows x 512 dims
    float inv[4];
    #pragma unroll
    for (int r = 0; r < 4; r++) inv[r] = 1.0f / dacc[r];
    #pragma unroll
    for (int et = 0; et < 32; et++)
      #pragma unroll
      for (int r = 0; r < 4; r++) {
        int q = q0w + lg * 4 + r;
        out[((size_t)(batch * LSEQ + q)) * DIM + et * 16 + l15] = oacc[et][r] * inv[r];
      }
  }
}

extern "C" void kernel_launch(void* const* d_in, const int* in_sizes, int n_in,
                              void* d_out, int out_size, void* d_ws, size_t ws_size,
                              hipStream_t stream) {
  const float* Ez = (const float*)d_in[0];
  const float* Wq = (const float*)d_in[1];
  const float* Wk = (const float*)d_in[2];
  const float* Wv = (const float*)d_in[3];
  const int* zp = (const int*)d_in[4];
  float* out = (float*)d_out;
  short* Qb = (short*)d_ws;
  short* Kb = Qb + (size_t)NB * LSEQ * DIM;
  short* Vtb = Kb + (size_t)NB * LSEQ * DIM;
  short* Wb = (short*)d_out;  // scratch: proj completes before attn writes out
  hipLaunchKernelGGL(wcvt_kernel, dim3(384), dim3(256), 0, stream,
                     Wq, Wk, Wv, zp, Wb);
  hipLaunchKernelGGL(proj_kernel, dim3(1024, 1, 3), dim3(512), 0, stream,
                     Ez, Wb, Qb, Kb, Vtb);
  hipLaunchKernelGGL(attn_kernel, dim3(32, 8), dim3(512), 0, stream,
                     Qb, Kb, Vtb, out);
}

// Round 15
// 420.006 us; speedup vs baseline: 1.3610x; 1.3610x over previous
//
#include <hip/hip_runtime.h>
#include <hip/hip_bf16.h>

// SelfAttention: out = softmax(causal((Ez Wq^T)(Ez Wk^T)^T / sqrt(512))) (Ez Wv^T)
// B=32, L=2048, DIM=512. f32 in/out; bf16 MFMA internally.
// ws: Qb (bf16, Q*SCALE*LOG2E), Kb (bf16), Vtb (bf16, [b][t][e][32] tile-contig,
// chunk-XOR pre-baked). Wb (bf16 [g][kt][n][32], swizzled) in d_out scratch.
// R15 = R12 (proven best) + in-wave lagged PV: iter t interleaves QK(t) with
// PV(t-1) MFMAs in one block (P kept in regs); V staged one iter late so the
// dbuf parity works out. No barrier-structure change.

typedef __attribute__((ext_vector_type(8))) short short8;
typedef __attribute__((ext_vector_type(4))) short short4v;
typedef __attribute__((ext_vector_type(4))) float f32x4;

#define DIM 512
#define LSEQ 2048
#define NB 32
#define SCALE 0.04419417382415922f
#define LOG2E 1.4426950408889634f

__device__ __forceinline__ short f2bs(float f) {
  __hip_bfloat16 h = __float2bfloat16(f);
  return __builtin_bit_cast(short, h);
}

__device__ __forceinline__ void gld16(const void* g, void* l) {
  __builtin_amdgcn_global_load_lds(
      (const unsigned int __attribute__((address_space(1)))*)g,
      (unsigned int __attribute__((address_space(3)))*)l, 16, 0, 0);
}

// ---- W[z] f32 -> bf16, layout [g][kt][n][32 d-chunk-swizzled] --------------
__global__ __launch_bounds__(256) void wcvt_kernel(
    const float* __restrict__ Wq, const float* __restrict__ Wk,
    const float* __restrict__ Wv, const int* __restrict__ zp,
    short* __restrict__ Wb) {
  int z = *zp;
  int i = blockIdx.x * 256 + threadIdx.x;
  int g = i >> 15;
  int off = (i & 32767) * 8;                   // flat [n][d], d fast
  int n = off >> 9, d0 = off & 511;
  int kt = d0 >> 5, c = d0 & 31;
  int sw = ((c >> 3) ^ ((n >> 1) & 3));
  const float* src = (g == 0 ? Wq : (g == 1 ? Wk : Wv)) + (size_t)z * DIM * DIM + off;
  float4 a = *(const float4*)src, b = *(const float4*)(src + 4);
  short8 v;
  v[0]=f2bs(a.x); v[1]=f2bs(a.y); v[2]=f2bs(a.z); v[3]=f2bs(a.w);
  v[4]=f2bs(b.x); v[5]=f2bs(b.y); v[6]=f2bs(b.z); v[7]=f2bs(b.w);
  *(short8*)&Wb[((size_t)(g * 16 + kt) * 512 + n) * 32 + sw * 8] = v;
}

// ---- projection GEMM: C[m][n] = sum_d Ez[m][d] * W[n][d] -------------------
__global__ __launch_bounds__(512, 4) void proj_kernel(
    const float* __restrict__ Ez, const short* __restrict__ Wb,
    short* __restrict__ Qb, short* __restrict__ Kb, short* __restrict__ Vtb) {
  int g = blockIdx.z;
  const short* W = Wb + (size_t)g * 16 * 512 * 32;
  __shared__ short As[2][64 * 32];
  __shared__ short Bs[2][512 * 32];
  int tid = threadIdx.x, lane = tid & 63, wid = tid >> 6;
  int l15 = lane & 15, lg = lane >> 4;
  int m0 = blockIdx.x * 64;
  int sw = (l15 >> 1) & 3;
  f32x4 zero4 = {0.f, 0.f, 0.f, 0.f};
  f32x4 acc[4][4];
  #pragma unroll
  for (int mi = 0; mi < 4; mi++)
    #pragma unroll
    for (int ni = 0; ni < 4; ni++) acc[mi][ni] = zero4;

  int arow = tid >> 3, aq = tid & 7;
  int aoff = arow * 32 + (((aq >> 1) ^ ((arow >> 1) & 3)) << 3) + (aq & 1) * 4;
  const float* aptr = Ez + (size_t)(m0 + arow) * DIM + aq * 4;

  {  // prologue: stage kt=0
    float4 a = *(const float4*)aptr;
    short4v av;
    av[0]=f2bs(a.x); av[1]=f2bs(a.y); av[2]=f2bs(a.z); av[3]=f2bs(a.w);
    *(short4v*)&As[0][aoff] = av;
    #pragma unroll
    for (int ii = 0; ii < 4; ii++) {
      int s = wid * 4 + ii;
      gld16(W + s * 512 + lane * 8, &Bs[0][s * 512]);
    }
  }
  __syncthreads();

  #pragma unroll 2
  for (int kt = 0; kt < 16; kt++) {
    int cur = kt & 1;
    float4 a;
    if (kt < 15) {
      a = *(const float4*)(aptr + (kt + 1) * 32);
      #pragma unroll
      for (int ii = 0; ii < 4; ii++) {
        int s = wid * 4 + ii;
        gld16(W + (size_t)(kt + 1) * 16384 + s * 512 + lane * 8, &Bs[cur ^ 1][s * 512]);
      }
    }
    short8 af[4], bf[4];
    #pragma unroll
    for (int mi = 0; mi < 4; mi++)
      af[mi] = *(const short8*)&As[cur][(mi * 16 + l15) * 32 + ((lg ^ sw) << 3)];
    #pragma unroll
    for (int ni = 0; ni < 4; ni++)
      bf[ni] = *(const short8*)&Bs[cur][(wid * 64 + ni * 16 + l15) * 32 + ((lg ^ sw) << 3)];
    __builtin_amdgcn_s_setprio(1);
    #pragma unroll
    for (int mi = 0; mi < 4; mi++)
      #pragma unroll
      for (int ni = 0; ni < 4; ni++)
        acc[mi][ni] = __builtin_amdgcn_mfma_f32_16x16x32_bf16(af[mi], bf[ni], acc[mi][ni], 0, 0, 0);
    __builtin_amdgcn_s_setprio(0);
    if (kt < 15) {
      short4v av;
      av[0]=f2bs(a.x); av[1]=f2bs(a.y); av[2]=f2bs(a.z); av[3]=f2bs(a.w);
      *(short4v*)&As[cur ^ 1][aoff] = av;
    }
    __syncthreads();
  }

  if (g == 2) {
    #pragma unroll
    for (int mi = 0; mi < 4; mi++) {
      int gm0 = m0 + mi * 16 + lg * 4;
      int b = gm0 >> 11, l0 = gm0 & (LSEQ - 1);
      int t = l0 >> 5, c0 = l0 & 31;
      #pragma unroll
      for (int ni = 0; ni < 4; ni++) {
        int e = wid * 64 + ni * 16 + l15;
        short4v v;
        v[0]=f2bs(acc[mi][ni][0]); v[1]=f2bs(acc[mi][ni][1]);
        v[2]=f2bs(acc[mi][ni][2]); v[3]=f2bs(acc[mi][ni][3]);
        size_t idx = ((size_t)(b * 64 + t) * 512 + e) * 32
                     + (((c0 >> 3) ^ ((e >> 1) & 3)) << 3) + (c0 & 7);
        *(short4v*)&Vtb[idx] = v;   // tile-contiguous V, read-swizzle pre-baked
      }
    }
  } else {
    short* dst = (g == 0 ? Qb : Kb);
    float sc = (g == 0 ? SCALE * LOG2E : 1.0f);  // Q pre-scaled, exp2 domain
    #pragma unroll
    for (int mi = 0; mi < 4; mi++) {
      int gm0 = m0 + mi * 16 + lg * 4;
      #pragma unroll
      for (int ni = 0; ni < 4; ni++) {
        int gn = wid * 64 + ni * 16 + l15;
        #pragma unroll
        for (int r = 0; r < 4; r++)
          dst[(size_t)(gm0 + r) * DIM + gn] = f2bs(acc[mi][ni][r] * sc);
      }
    }
  }
}

// ---- flash attention (causal) ----------------------------------------------
// R12 base + in-wave lagged PV. V staged one iteration late: iter t stages
// K(t+1) into Kl[cur^1] and V(t) into Vl[cur]; PV(t-1) reads Vl[cur^1].
__device__ __forceinline__ void stage_k(const short* __restrict__ Kb,
                                        short* Klbuf,
                                        int batch, int t, int wid, int lane) {
  #pragma unroll
  for (int ii = 0; ii < 4; ii++) {          // K: rows wid, wid+8, wid+16, wid+24
    int r = wid + ii * 8;                   // r&7 == wid
    const short* src = Kb + (size_t)(batch * LSEQ + t * 32 + r) * DIM + ((lane ^ wid) * 8);
    gld16(src, Klbuf + r * 512);
  }
}
__device__ __forceinline__ void stage_v(const short* __restrict__ Vtb,
                                        short* Vlbuf,
                                        int batch, int t, int wid, int lane) {
  const short* vt = Vtb + (size_t)(batch * 64 + t) * 16384;  // contiguous 32KB
  #pragma unroll
  for (int ii = 0; ii < 4; ii++) {
    int s = wid * 4 + ii;
    gld16(vt + s * 512 + lane * 8, Vlbuf + s * 512);
  }
}

__global__ __launch_bounds__(512, 2) void attn_kernel(
    const short* __restrict__ Qb, const short* __restrict__ Kb,
    const short* __restrict__ Vtb, float* __restrict__ out) {
  __shared__ short Kl[2][32 * 512];   // 64 KB dbuf
  __shared__ short Vl[2][512 * 32];   // 64 KB dbuf
  __shared__ short P_lds[8][16][40];  // per-wave P transpose; 16B-aligned rows
  int tid = threadIdx.x, lane = tid & 63, wid = tid >> 6;
  int l15 = lane & 15, lg = lane >> 4;
  int batch = blockIdx.x;
  f32x4 zero4 = {0.f, 0.f, 0.f, 0.f};
  short8 ones;
  #pragma unroll
  for (int i = 0; i < 8; i++) ones[i] = (short)0x3F80;

  // lane-const LDS offsets (shorts):
  int a0 = (l15 >> 2) & 1, b0 = l15 & 3;
  int kqE = l15 * 512 + 8 * (lg ^ b0) + 32 * a0;  // even-kt base (+8192 for c=1)
  int kqO = l15 * 512 + 8 * (lg ^ b0) - 32 * a0;  // odd-kt base
  int voff = l15 * 32 + 8 * (lg ^ ((l15 >> 1) & 3));  // V base (+512*et)
  short* pw = &P_lds[wid][lg * 4][l15];               // P write (+40*r, +16*c)
  const short* pr = &P_lds[wid][l15][lg * 8];         // P read (A-frag, aligned)

  for (int qpass = 0; qpass < 2; qpass++) {
    int qt = qpass ? (int)blockIdx.y : 15 - (int)blockIdx.y;  // long pass first
    int qb0 = qt * 128;
    int q0w = qb0 + wid * 16;
    int nt = qt * 4 + 4;

    stage_k(Kb, Kl[0], batch, 0, wid, lane);  // prologue: K(0) only

    const short* qrow = Qb + (size_t)(batch * LSEQ + q0w + l15) * DIM;
    short8 qf[16];  // Q rows in regs (SCALE*LOG2E pre-folded)
    #pragma unroll
    for (int kt = 0; kt < 16; kt++) qf[kt] = *(const short8*)(qrow + kt * 32 + lg * 8);

    f32x4 oacc[32];
    #pragma unroll
    for (int i = 0; i < 32; i++) oacc[i] = zero4;
    f32x4 dacc = zero4;   // per-row softmax denominator (via ones-MFMA)
    float mrun = -1e30f;  // wave-uniform running max (exp2 domain)
    short8 pa;            // P fragment of tile t-1 (valid when act(t-1))

    __syncthreads();  // drains prologue stage (vmcnt) + syncs

    for (int t = 0; t < nt; t++) {
      int cur = t & 1;
      if (t + 1 < nt)
        stage_k(Kb, Kl[cur ^ 1], batch, t + 1, wid, lane);
      stage_v(Vtb, Vl[cur], batch, t, wid, lane);  // V(t): consumed iter t+1

      bool act = (t * 32 <= q0w + 15);
      bool actp = (t > 0) && ((t - 1) * 32 <= q0w + 15);
      f32x4 sacc[2] = {zero4, zero4};
      if (act && actp) {
        // merged block: QK(t) interleaved with PV(t-1) (independent streams)
        const short* pE = Kl[cur] + kqE;
        const short* pO = Kl[cur] + kqO;
        const short* vb = Vl[cur ^ 1] + voff;
        __builtin_amdgcn_s_setprio(1);
        dacc = __builtin_amdgcn_mfma_f32_16x16x32_bf16(pa, ones, dacc, 0, 0, 0);
        #pragma unroll
        for (int kt = 0; kt < 16; kt += 2) {
          short8 k0 = *(const short8*)(pE + 32 * kt);
          short8 k1 = *(const short8*)(pE + 8192 + 32 * kt);
          sacc[0] = __builtin_amdgcn_mfma_f32_16x16x32_bf16(qf[kt], k0, sacc[0], 0, 0, 0);
          sacc[1] = __builtin_amdgcn_mfma_f32_16x16x32_bf16(qf[kt], k1, sacc[1], 0, 0, 0);
          short8 v0 = *(const short8*)(vb + (kt * 2) * 512);
          short8 v1 = *(const short8*)(vb + (kt * 2 + 1) * 512);
          oacc[kt * 2] = __builtin_amdgcn_mfma_f32_16x16x32_bf16(pa, v0, oacc[kt * 2], 0, 0, 0);
          oacc[kt * 2 + 1] = __builtin_amdgcn_mfma_f32_16x16x32_bf16(pa, v1, oacc[kt * 2 + 1], 0, 0, 0);
          short8 k2 = *(const short8*)(pO + 32 * (kt + 1));
          short8 k3 = *(const short8*)(pO + 8192 + 32 * (kt + 1));
          sacc[0] = __builtin_amdgcn_mfma_f32_16x16x32_bf16(qf[kt + 1], k2, sacc[0], 0, 0, 0);
          sacc[1] = __builtin_amdgcn_mfma_f32_16x16x32_bf16(qf[kt + 1], k3, sacc[1], 0, 0, 0);
          short8 v2 = *(const short8*)(vb + (kt * 2 + 2) * 512);
          short8 v3 = *(const short8*)(vb + (kt * 2 + 3) * 512);
          oacc[kt * 2 + 2] = __builtin_amdgcn_mfma_f32_16x16x32_bf16(pa, v2, oacc[kt * 2 + 2], 0, 0, 0);
          oacc[kt * 2 + 3] = __builtin_amdgcn_mfma_f32_16x16x32_bf16(pa, v3, oacc[kt * 2 + 3], 0, 0, 0);
        }
        __builtin_amdgcn_s_setprio(0);
      } else if (act) {  // t == 0: QK only
        const short* pE = Kl[cur] + kqE;
        const short* pO = Kl[cur] + kqO;
        __builtin_amdgcn_s_setprio(1);
        #pragma unroll
        for (int kt = 0; kt < 16; kt += 2) {
          short8 k0 = *(const short8*)(pE + 32 * kt);
          short8 k1 = *(const short8*)(pE + 8192 + 32 * kt);
          sacc[0] = __builtin_amdgcn_mfma_f32_16x16x32_bf16(qf[kt], k0, sacc[0], 0, 0, 0);
          sacc[1] = __builtin_amdgcn_mfma_f32_16x16x32_bf16(qf[kt], k1, sacc[1], 0, 0, 0);
          short8 k2 = *(const short8*)(pO + 32 * (kt + 1));
          short8 k3 = *(const short8*)(pO + 8192 + 32 * (kt + 1));
          sacc[0] = __builtin_amdgcn_mfma_f32_16x16x32_bf16(qf[kt + 1], k2, sacc[0], 0, 0, 0);
          sacc[1] = __builtin_amdgcn_mfma_f32_16x16x32_bf16(qf[kt + 1], k3, sacc[1], 0, 0, 0);
        }
        __builtin_amdgcn_s_setprio(0);
      } else if (actp) {  // transition tile: PV(t-1) only
        const short* vb = Vl[cur ^ 1] + voff;
        __builtin_amdgcn_s_setprio(1);
        dacc = __builtin_amdgcn_mfma_f32_16x16x32_bf16(pa, ones, dacc, 0, 0, 0);
        #pragma unroll
        for (int et = 0; et < 32; et++) {
          short8 bv = *(const short8*)(vb + et * 512);
          oacc[et] = __builtin_amdgcn_mfma_f32_16x16x32_bf16(pa, bv, oacc[et], 0, 0, 0);
        }
        __builtin_amdgcn_s_setprio(0);
      }
      if (act) {  // softmax(t) -> P_lds -> pa (regs) for next iter's PV
        if (t * 32 + 31 > q0w) {  // diagonal tiles only: causal mask
          #pragma unroll
          for (int r = 0; r < 4; r++) {
            int q = q0w + lg * 4 + r;
            if (t * 32 + l15 > q) sacc[0][r] = -1e30f;
            if (t * 32 + 16 + l15 > q) sacc[1][r] = -1e30f;
          }
        }
        float lm = fmaxf(
            fmaxf(fmaxf(sacc[0][0], sacc[0][1]), fmaxf(sacc[0][2], sacc[0][3])),
            fmaxf(fmaxf(sacc[1][0], sacc[1][1]), fmaxf(sacc[1][2], sacc[1][3])));
        if (__any(lm > mrun + 11.5f)) {  // rare: raise the wave max
          float mx = lm;
          #pragma unroll
          for (int off = 1; off < 64; off <<= 1) mx = fmaxf(mx, __shfl_xor(mx, off, 64));
          float alpha = exp2f(mrun - mx);
          mrun = mx;
          dacc[0] *= alpha; dacc[1] *= alpha; dacc[2] *= alpha; dacc[3] *= alpha;
          #pragma unroll
          for (int et = 0; et < 32; et++) {
            oacc[et][0] *= alpha; oacc[et][1] *= alpha;
            oacc[et][2] *= alpha; oacc[et][3] *= alpha;
          }
        }
        #pragma unroll
        for (int r = 0; r < 4; r++) {
          pw[r * 40] = f2bs(exp2f(sacc[0][r] - mrun));
          pw[r * 40 + 16] = f2bs(exp2f(sacc[1][r] - mrun));
        }
        pa = *(const short8*)pr;  // wave-local RAW
      }
      __syncthreads();  // drains prefetch (vmcnt) + releases buffers
    }
    // drain: PV(nt-1) for waves active at the last tile
    if ((nt - 1) * 32 <= q0w + 15) {
      const short* vb = Vl[(nt - 1) & 1] + voff;
      dacc = __builtin_amdgcn_mfma_f32_16x16x32_bf16(pa, ones, dacc, 0, 0, 0);
      #pragma unroll
      for (int et = 0; et < 32; et++) {
        short8 bv = *(const short8*)(vb + et * 512);
        oacc[et] = __builtin_amdgcn_mfma_f32_16x16x32_bf16(pa, bv, oacc[et], 0, 0, 0);
      }
    }
    // epilogue: per-wave divide by denominator, write 16 q-rows x 512 dims
    float inv[4];
    #pragma unroll
    for (int r = 0; r < 4; r++) inv[r] = 1.0f / dacc[r];
    #pragma unroll
    for (int et = 0; et < 32; et++)
      #pragma unroll
      for (int r = 0; r < 4; r++) {
        int q = q0w + lg * 4 + r;
        out[((size_t)(batch * LSEQ + q)) * DIM + et * 16 + l15] = oacc[et][r] * inv[r];
      }
    __syncthreads();  // LDS reuse safe before next qpass
  }
}

extern "C" void kernel_launch(void* const* d_in, const int* in_sizes, int n_in,
                              void* d_out, int out_size, void* d_ws, size_t ws_size,
                              hipStream_t stream) {
  const float* Ez = (const float*)d_in[0];
  const float* Wq = (const float*)d_in[1];
  const float* Wk = (const float*)d_in[2];
  const float* Wv = (const float*)d_in[3];
  const int* zp = (const int*)d_in[4];
  float* out = (float*)d_out;
  short* Qb = (short*)d_ws;
  short* Kb = Qb + (size_t)NB * LSEQ * DIM;
  short* Vtb = Kb + (size_t)NB * LSEQ * DIM;
  short* Wb = (short*)d_out;  // scratch: proj completes before attn writes out
  hipLaunchKernelGGL(wcvt_kernel, dim3(384), dim3(256), 0, stream,
                     Wq, Wk, Wv, zp, Wb);
  hipLaunchKernelGGL(proj_kernel, dim3(1024, 1, 3), dim3(512), 0, stream,
                     Ez, Wb, Qb, Kb, Vtb);
  hipLaunchKernelGGL(attn_kernel, dim3(32, 8), dim3(512), 0, stream,
                     Qb, Kb, Vtb, out);
}